// Round 19
// baseline (193.072 us; speedup 1.0000x reference)
//
#include <hip/hip_runtime.h>
#include <hip/hip_fp16.h>

#define DI __device__ __forceinline__

constexpr int NGRAPH = 500;
constexpr int EDGES  = 800000;
constexpr int NNODE  = 50000;
constexpr int CAP    = 64;            // slots per dst bin (Poisson mean 16; pow2 for shifts)
constexpr int SCAT_BLOCKS = (EDGES + 255) / 256;   // 3125

// ---- workspace layout (4-byte units) ----
constexpr size_t WI_CURS  = 0;                               // [50000]
constexpr size_t WI_SMETA = 50048;                           // [50000*64]
constexpr size_t WF_PREP  = WI_SMETA + (size_t)NNODE * CAP;  // 656 floats (pad 672)
constexpr size_t WF_WFRAG = WF_PREP + 672;                   // uint4[5120] (20480 words)
constexpr size_t WH_WC    = WF_WFRAG + 20480;                // f16[NGRAPH*2048*4]

// ---- LDS layout (bytes), total 72584 -> 2 blocks/CU ----
constexpr int S_H    = 0;        // f16 h[100][40] (cols 0..31 used)
constexpr int S_HP   = 8000;     // f16 hp[100][128] (col c -> d=c>>2,h=c&3), XOR-swizzled
constexpr int S_U    = 33600;    // f16 U[100][132]  (4 rels per pass)
constexpr int S_EH   = 60000;    // f32[100][4]
constexpr int S_ET   = 61600;    // f32[100][4]
constexpr int S_RA   = 63200;    // f32[16][4]
constexpr int S_ESG  = 63456;    // f32[4]
constexpr int S_AH   = 63472;    // f16[128] attn_h in hp-col order
constexpr int S_AT   = 63728;    // f16[128]
constexpr int S_MLDS = 63984;    // i32[2048] dst-sorted edge meta
constexpr int S_RP   = 72176;    // i32[102] rowptr
constexpr int S_TOTAL = 72584;
constexpr int UROW = 132;

typedef _Float16 f16x8 __attribute__((ext_vector_type(8)));
typedef _Float16 f16x2 __attribute__((ext_vector_type(2)));
typedef float f32x4 __attribute__((ext_vector_type(4)));

DI float lrelu(float x) { return x >= 0.f ? x : 0.2f * x; }
DI f16x8 u4_to_f16x8(uint4 u) { f16x8 r; __builtin_memcpy(&r, &u, 16); return r; }
DI f16x8 two_u2(uint2 a, uint2 b) { return u4_to_f16x8(make_uint4(a.x, a.y, b.x, b.y)); }
DI float h2f(unsigned short u) { __half hv; __builtin_memcpy(&hv, &u, 2); return __half2float(hv); }

// f32 += half2 . half2 via v_dot2_f32_f16
DI float fdot2u(unsigned a, unsigned b, float c) {
    f16x2 av, bv;
    __builtin_memcpy(&av, &a, 4);
    __builtin_memcpy(&bv, &b, 4);
    return __builtin_amdgcn_fdot2(av, bv, c, false);
}

// hp swizzle: half-index for (node n, col c); XOR bits 3..5 with n&7 (16B granularity)
DI int hpIdx(int n, int c) { return n * 128 + (c ^ ((n & 7) << 3)); }

// ---------------- merged prep: scatter-by-dst + prep folds + MFMA fragments ----------------
__global__ void k_prep(const int* __restrict__ src, const int* __restrict__ dst,
                       const int* __restrict__ rt, int* __restrict__ curs,
                       int* __restrict__ smeta,
                       const float* __restrict__ rel_table, const float* __restrict__ Wr,
                       const float* __restrict__ br, const float* __restrict__ We,
                       const float* __restrict__ be, const float* __restrict__ attn_r,
                       const float* __restrict__ attn_rs, const float* __restrict__ attn_s,
                       const float* __restrict__ W, float* __restrict__ prep,
                       uint4* __restrict__ wf) {
    __shared__ float wra[2][32][4];
    __shared__ float sbias[2][3][4];
    int bb = blockIdx.x, t = threadIdx.x;
    if (bb < SCAT_BLOCKS) {
        int e = bb * 256 + t;
        if (e >= EDGES) return;
        int s = src[e], d = dst[e], r = rt[e];
        int g = (unsigned)d / 100u;
        int pos = atomicAdd(&curs[d], 1);
        if (pos < CAP)
            smeta[((size_t)d << 6) + pos] = (s - g * 100) | (r << 7) | (e << 11);
        return;
    }
    int b = bb - SCAT_BLOCKS;
    if (b == 0) {
        {
            int l = t >> 7, k = (t >> 2) & 31, h = t & 3;
            float a = 0.f, b2 = 0.f, c = 0.f;
            for (int d2 = 0; d2 < 32; ++d2) {
                float w1 = Wr[(size_t)(l*32 + k)*128 + h*32 + d2];
                float w2 = We[(size_t)(l*32 + k)*128 + h*32 + d2];
                a  += w1 * attn_r [l*128 + h*32 + d2];
                b2 += w1 * attn_rs[l*128 + h*32 + d2];
                c  += w2 * attn_s [l*128 + h*32 + d2];
            }
            wra[l][k][h] = a;
            prep[128 + (l*32 + k)*4 + h] = b2;
            prep[384 + (l*32 + k)*4 + h] = c;
        }
        if (t < 24) {
            int l = t / 12, which = (t % 12) / 4, h = t % 4;
            const float* bp = (which == 2) ? be : br;
            const float* ap = (which == 0) ? attn_r : (which == 1 ? attn_rs : attn_s);
            float s = 0.f;
            for (int d2 = 0; d2 < 32; ++d2) s += bp[l*128 + h*32 + d2] * ap[l*128 + h*32 + d2];
            sbias[l][which][h] = s;
        }
        __syncthreads();
        if (t < 128) {
            int l = t >> 6, r = (t >> 2) & 15, h = t & 3;
            float s = sbias[l][0][h];
            for (int k = 0; k < 32; ++k) s += rel_table[r*32 + k] * wra[l][k][h];
            prep[(l*16 + r)*4 + h] = s;
        }
        if (t < 8) {
            int l = t >> 2, h = t & 3;
            prep[640 + l*4 + h] = sbias[l][1][h];
            prep[648 + l*4 + h] = sbias[l][2][h];
        }
    } else if (b <= 16) {
        // W fragments (f16): wf[((l*16+rel)*2+Nt)*64 + ln]
        int fi = (b - 1) * 256 + t;
        int ln = fi & 63, Nt = (fi >> 6) & 1, rel = (fi >> 7) & 15, l = fi >> 11;
        int j = Nt*16 + (ln & 15), k0 = (ln >> 4) << 3;
        unsigned short fr[8];
        #pragma unroll
        for (int i = 0; i < 8; ++i) {
            __half hv = __float2half(W[(((size_t)l*16 + rel)*32 + k0 + i)*32 + j]);
            __builtin_memcpy(&fr[i], &hv, 2);
        }
        uint4 o;
        o.x = fr[0] | ((unsigned)fr[1] << 16);
        o.y = fr[2] | ((unsigned)fr[3] << 16);
        o.z = fr[4] | ((unsigned)fr[5] << 16);
        o.w = fr[6] | ((unsigned)fr[7] << 16);
        wf[fi] = o;
    } else {
        // We fragments (f16, column-permuted): col c -> phys (c&3)*32+(c>>2)
        int fi = (b - 17) * 256 + t;
        int ln = fi & 63, Nt = (fi >> 6) & 7, l = fi >> 9;
        int c = Nt*16 + (ln & 15);
        int phys = (c & 3)*32 + (c >> 2);
        int k0 = (ln >> 4) << 3;
        unsigned short fr[8];
        #pragma unroll
        for (int i = 0; i < 8; ++i) {
            __half hv = __float2half(We[(size_t)l*4096 + (k0 + i)*128 + phys]);
            __builtin_memcpy(&fr[i], &hv, 2);
        }
        uint4 o;
        o.x = fr[0] | ((unsigned)fr[1] << 16);
        o.y = fr[2] | ((unsigned)fr[3] << 16);
        o.z = fr[4] | ((unsigned)fr[5] << 16);
        o.w = fr[6] | ((unsigned)fr[7] << 16);
        wf[4096 + fi] = o;
    }
}

// ---------------- fused per-graph forward: 512 threads, 2 blocks/CU, 4 rel-quad passes ----------------
__global__ void __launch_bounds__(512, 4)
k_fused(const float* __restrict__ state, const float* __restrict__ rw,
        const float* __restrict__ code_emb, const float* __restrict__ h_bias,
        const float* __restrict__ be, const float* __restrict__ attn_h,
        const float* __restrict__ attn_t, const int* __restrict__ node_ids,
        const int* __restrict__ curs, const int* __restrict__ smeta,
        const float* __restrict__ prep, const uint4* __restrict__ wf,
        unsigned short* __restrict__ wc,
        float* __restrict__ xout, float* __restrict__ relOut, float* __restrict__ edgeOut) {
    extern __shared__ char smem[];
    __half* hH  = (__half*)(smem + S_H);
    __half* hpH = (__half*)(smem + S_HP);
    __half* Uh  = (__half*)(smem + S_U);
    float* ehp  = (float*)(smem + S_EH);
    float* etp  = (float*)(smem + S_ET);
    float* rap  = (float*)(smem + S_RA);
    float* esgp = (float*)(smem + S_ESG);
    __half* sAHh = (__half*)(smem + S_AH);
    __half* sATh = (__half*)(smem + S_AT);
    int*   mlds = (int*)(smem + S_MLDS);
    int*   rp   = (int*)(smem + S_RP);
    const uint4* wfe = wf + 4096;

    const int g = blockIdx.x;
    const int t = threadIdx.x;
    const int lane = t & 63, w = t >> 6;          // 8 waves
    const int ln15 = lane & 15, q = lane >> 4, q8 = q << 3;
    // P7/P8 tiles: tiA = w (0..7), tiB = w+8 (8..13, waves 0..5)
    const int MtA = w % 7, NtA = w / 7;
    const int MtB = (w + 8) % 7, NtB = (w + 8) / 7;
    const bool hasB = (w < 6);
    // X1 column-group: wave = cg (8 groups x 16 cols)
    const int colc = w * 16 + ln15;
    const int physc = (colc & 3) * 32 + (colc >> 2);

    unsigned short* wcg = wc + ((size_t)g << 13);     // 2048 edges x 4 halves
    const uint2* wcu = (const uint2*)wcg;

    // P0: h0 = code_emb[node_ids]; rowptr scan; CSR stage
    for (int i = t; i < 1600; i += 512) {
        int n = i >> 4, dp = i & 15;
        int id = node_ids[g * 100 + n];
        float2 v = *(const float2*)&code_emb[(size_t)id * 32 + dp * 2];
        *(__half2*)&hH[n * 40 + dp * 2] = __floats2half2_rn(v.x, v.y);
    }
    if (t < 100) { int c = curs[g * 100 + t]; rp[t + 1] = c < CAP ? c : CAP; }
    if (t == 0) rp[0] = 0;
    __syncthreads();
    for (int o = 1; o < 128; o <<= 1) {
        int v = 0;
        if (t <= 100 && t >= o) v = rp[t - o];
        __syncthreads();
        if (t <= 100 && t >= o) rp[t] += v;
        __syncthreads();
    }
    for (int i = t; i < 100 * CAP; i += 512) {
        int bin = i >> 6, pos = i & 63;
        int lo = rp[bin], cnt = rp[bin + 1] - lo;
        if (pos < cnt)
            mlds[lo + pos] = smeta[(((size_t)(g * 100 + bin)) << 6) + pos];
    }

    for (int l = 0; l < 2; ++l) {
        __syncthreads();   // B0: h/CSR ready

        // ---- X1: stage sAH/sAT (f16); MFMA hp = h@We + be; P1 rel-att ----
        if (t < 128) {
            sAHh[t] = __float2half(attn_h[l * 128 + (t & 3) * 32 + (t >> 2)]);
            sATh[t] = __float2half(attn_t[l * 128 + (t & 3) * 32 + (t >> 2)]);
        }
        {
            uint4 bwe = wfe[(l * 8 + w) * 64 + lane];
            f16x8 bw = u4_to_f16x8(bwe);
            float beC = be[l * 128 + physc];
            f32x4 z = {0.f, 0.f, 0.f, 0.f};
            for (int Mt = 0; Mt < 7; ++Mt) {
                const __half* hr = hH + (Mt * 16 + ln15) * 40 + q8;
                f32x4 pc = __builtin_amdgcn_mfma_f32_16x16x32_f16(
                    two_u2(*(const uint2*)hr, *(const uint2*)(hr + 4)), bw, z, 0, 0, 0);
                #pragma unroll
                for (int i = 0; i < 4; ++i) {
                    int n = Mt * 16 + q * 4 + i;
                    if (n < 100) hpH[hpIdx(n, colc)] = __float2half(pc[i] + beC);
                }
            }
        }
        {   // P1: relation attention (all waves redundantly; benign identical writes)
            int k32 = lane & 31;
            float sG = state[g * 32 + k32];
            float4 frs = *(const float4*)&prep[128 + l * 128 + k32 * 4];
            float4 fes = *(const float4*)&prep[384 + l * 128 + k32 * 4];
            float p0 = sG * frs.x, p1 = sG * frs.y, p2 = sG * frs.z, p3 = sG * frs.w;
            float q0 = sG * fes.x, q1 = sG * fes.y, q2 = sG * fes.z, q3 = sG * fes.w;
            #pragma unroll
            for (int m = 1; m < 32; m <<= 1) {
                p0 += __shfl_xor(p0, m); p1 += __shfl_xor(p1, m);
                p2 += __shfl_xor(p2, m); p3 += __shfl_xor(p3, m);
                q0 += __shfl_xor(q0, m); q1 += __shfl_xor(q1, m);
                q2 += __shfl_xor(q2, m); q3 += __shfl_xor(q3, m);
            }
            int h = lane & 3;
            float esh  = (h & 2) ? ((h & 1) ? p3 : p2) : ((h & 1) ? p1 : p0);
            float esgh = (h & 2) ? ((h & 1) ? q3 : q2) : ((h & 1) ? q1 : q0);
            esh  += prep[640 + l * 4 + h];
            esgh += prep[648 + l * 4 + h];
            if (lane < 4) esgp[lane] = esgh;
            float er = prep[l * 64 + lane];
            float ex = __expf(lrelu(er + esh));
            float s = ex;
            s += __shfl_xor(s, 4); s += __shfl_xor(s, 8);
            s += __shfl_xor(s, 16); s += __shfl_xor(s, 32);
            rap[lane] = ex / s;
        }
        __syncthreads();   // B1: hp/sAH/sAT/rap/esg ready

        // ---- A0: eh/et per src node (owner = s; no atomics) ----
        if (t < 100) {
            int s = t;
            int sw = (s & 7) << 3;
            float eh[4] = {0, 0, 0, 0}, et[4] = {0, 0, 0, 0};
            #pragma unroll 4
            for (int i = 0; i < 16; ++i) {
                uint4 hv = *(const uint4*)&hpH[s * 128 + ((i * 8) ^ sw)];
                unsigned short hu[8];
                __builtin_memcpy(hu, &hv, 16);
                #pragma unroll
                for (int k = 0; k < 8; ++k) {
                    float f = h2f(hu[k]);
                    eh[k & 3] += f * __half2float(sAHh[i * 8 + k]);
                    et[k & 3] += f * __half2float(sATh[i * 8 + k]);
                }
            }
            *(float4*)&ehp[s * 4] = make_float4(eh[0], eh[1], eh[2], eh[3]);
            *(float4*)&etp[s * 4] = make_float4(et[0], et[1], et[2], et[3]);
        }
        __syncthreads();   // B1b: eh/et ready

        // ---- A: den per (dst, head); then packed coefficients to global wc ----
        if (t < 400) {
            int d = t >> 2, h = t & 3;
            int lo = rp[d], hi = rp[d + 1];
            float etd = etp[d * 4 + h] + esgp[h];
            float den = 0.f;
            for (int e = lo; e < hi; ++e) {
                int m = mlds[e];
                den += __expf(lrelu(ehp[(m & 127) * 4 + h] + etd));
            }
            float inv = 1.f / den;
            bool wAtt = (l == 1);
            for (int e = lo; e < hi; ++e) {
                int m = mlds[e];
                int r = (m >> 7) & 15;
                float a = __expf(lrelu(ehp[(m & 127) * 4 + h] + etd)) * inv;
                __half ch = __float2half(a * rap[r * 4 + h]);
                __builtin_memcpy(&wcg[e * 4 + h], &ch, 2);
                if (wAtt) {
                    int oe = (m >> 11) & 0xFFFFF;
                    edgeOut[(size_t)oe * 4 + h] = a;
                    relOut[(size_t)oe * 4 + h] = rap[r * 4 + h];
                }
            }
        }
        __syncthreads();   // B2: coefs ready (vmcnt drained by barrier)

        // ---- 4 passes over relation quads: zero U -> scatter -> MFMA accumulate ----
        f32x4 accA = {0.f, 0.f, 0.f, 0.f};
        f32x4 accB = {0.f, 0.f, 0.f, 0.f};
        for (int p = 0; p < 4; ++p) {
            for (int i = t; i < 1650; i += 512) ((uint4*)(smem + S_U))[i] = make_uint4(0, 0, 0, 0);
            __syncthreads();   // U zeroed

            // B: U accumulation per (dst, dim-octet j in 0..3), rels [4p, 4p+4)
            if (t < 400) {
                int d = t >> 2, j = t & 3;      // dims [j*8, j*8+8)
                int lo = rp[d], hi = rp[d + 1];
                for (int e = lo; e < hi; ++e) {
                    int m = mlds[e];
                    int r = (m >> 7) & 15;
                    if ((r >> 2) != p) continue;
                    int s = m & 127;
                    uint2 cc = wcu[e];
                    int sw = (s & 7) << 3;
                    uint4 hv0 = *(const uint4*)&hpH[s * 128 + ((j * 32) ^ sw)];
                    uint4 hv1 = *(const uint4*)&hpH[s * 128 + ((j * 32 + 8) ^ sw)];
                    uint4 hv2 = *(const uint4*)&hpH[s * 128 + ((j * 32 + 16) ^ sw)];
                    uint4 hv3 = *(const uint4*)&hpH[s * 128 + ((j * 32 + 24) ^ sw)];
                    float v0 = fdot2u(cc.x, hv0.x, fdot2u(cc.y, hv0.y, 0.f));
                    float v1 = fdot2u(cc.x, hv0.z, fdot2u(cc.y, hv0.w, 0.f));
                    float v2 = fdot2u(cc.x, hv1.x, fdot2u(cc.y, hv1.y, 0.f));
                    float v3 = fdot2u(cc.x, hv1.z, fdot2u(cc.y, hv1.w, 0.f));
                    float v4 = fdot2u(cc.x, hv2.x, fdot2u(cc.y, hv2.y, 0.f));
                    float v5 = fdot2u(cc.x, hv2.z, fdot2u(cc.y, hv2.w, 0.f));
                    float v6 = fdot2u(cc.x, hv3.x, fdot2u(cc.y, hv3.y, 0.f));
                    float v7 = fdot2u(cc.x, hv3.z, fdot2u(cc.y, hv3.w, 0.f));
                    __half2* up = (__half2*)(Uh + d * UROW + (r & 3) * 32 + j * 8);
                    up[0] = __hadd2(up[0], __floats2half2_rn(v0, v1));
                    up[1] = __hadd2(up[1], __floats2half2_rn(v2, v3));
                    up[2] = __hadd2(up[2], __floats2half2_rn(v4, v5));
                    up[3] = __hadd2(up[3], __floats2half2_rn(v6, v7));
                }
            }
            __syncthreads();   // U complete for this quad

            // P7: 4-rel MFMA chain for this quad (accumulate across passes)
            #pragma unroll
            for (int kq = 0; kq < 4; ++kq) {
                int rel = p * 4 + kq;
                {
                    uint4 bAu = wf[((l * 16 + rel) * 2 + NtA) * 64 + lane];
                    const __half* up = Uh + (MtA * 16 + ln15) * UROW + kq * 32 + q8;
                    f16x8 af = two_u2(*(const uint2*)up, *(const uint2*)(up + 4));
                    accA = __builtin_amdgcn_mfma_f32_16x16x32_f16(af, u4_to_f16x8(bAu), accA, 0, 0, 0);
                }
                if (hasB) {
                    uint4 bBu = wf[((l * 16 + rel) * 2 + NtB) * 64 + lane];
                    const __half* up = Uh + (MtB * 16 + ln15) * UROW + kq * 32 + q8;
                    f16x8 af = two_u2(*(const uint2*)up, *(const uint2*)(up + 4));
                    accB = __builtin_amdgcn_mfma_f32_16x16x32_f16(af, u4_to_f16x8(bBu), accB, 0, 0, 0);
                }
            }
            __syncthreads();   // U consumed; safe to re-zero next pass
        }

        // P8: h = relu(0.5*(agg+bias) + 0.5*h)
        {
            int dcol = NtA * 16 + ln15;
            float bias = h_bias[l * 32 + dcol];
            #pragma unroll
            for (int i = 0; i < 4; ++i) {
                int n = MtA * 16 + q * 4 + i;
                if (n < 100) {
                    float hold = __half2float(hH[n * 40 + dcol]);
                    float hn = fmaxf(0.f, 0.5f * (accA[i] + bias) + 0.5f * hold);
                    hH[n * 40 + dcol] = __float2half(hn);
                }
            }
        }
        if (hasB) {
            int dcol = NtB * 16 + ln15;
            float bias = h_bias[l * 32 + dcol];
            #pragma unroll
            for (int i = 0; i < 4; ++i) {
                int n = MtB * 16 + q * 4 + i;
                if (n < 100) {
                    float hold = __half2float(hH[n * 40 + dcol]);
                    float hn = fmaxf(0.f, 0.5f * (accB[i] + bias) + 0.5f * hold);
                    hH[n * 40 + dcol] = __float2half(hn);
                }
            }
        }
    }
    __syncthreads();   // h final

    // P9: readout x[g] = sum_n h[n] * rw[n]   (red buffer reuses U region)
    float* redp = (float*)(smem + S_U);
    {
        int part = t >> 5, d = t & 31;
        float acc = 0.f;
        for (int n = part; n < 100; n += 16)
            acc += __half2float(hH[n * 40 + d]) * rw[g * 100 + n];
        redp[part * 32 + d] = acc;
    }
    __syncthreads();
    if (t < 32) {
        float s = 0.f;
        #pragma unroll
        for (int p = 0; p < 16; ++p) s += redp[p * 32 + t];
        xout[g * 32 + t] = s;
    }
}

extern "C" void kernel_launch(void* const* d_in, const int* in_sizes, int n_in,
                              void* d_out, int out_size, void* d_ws, size_t ws_size,
                              hipStream_t stream) {
    const float* state     = (const float*)d_in[0];
    const float* rw        = (const float*)d_in[1];
    const float* code_emb  = (const float*)d_in[2];
    const float* rel_table = (const float*)d_in[3];
    const float* W         = (const float*)d_in[4];
    const float* h_bias    = (const float*)d_in[5];
    const float* Wr        = (const float*)d_in[6];
    const float* br        = (const float*)d_in[7];
    const float* We        = (const float*)d_in[8];
    const float* be        = (const float*)d_in[9];
    const float* attn_h    = (const float*)d_in[10];
    const float* attn_t    = (const float*)d_in[11];
    const float* attn_s    = (const float*)d_in[12];
    const float* attn_r    = (const float*)d_in[13];
    const float* attn_rs   = (const float*)d_in[14];
    const int* node_ids    = (const int*)d_in[15];
    const int* src         = (const int*)d_in[16];
    const int* dst         = (const int*)d_in[17];
    const int* rtype       = (const int*)d_in[18];

    float* out = (float*)d_out;
    float* xout = out;
    float* relOut = out + (size_t)NGRAPH * 32;
    float* edgeOut = relOut + (size_t)EDGES * 4;

    int* wsi = (int*)d_ws;
    float* wsf = (float*)d_ws;
    int* curs   = wsi + WI_CURS;
    int* smeta  = wsi + WI_SMETA;
    float* prep = wsf + WF_PREP;
    uint4* wfrag = (uint4*)(wsf + WF_WFRAG);
    unsigned short* wc = (unsigned short*)(wsf + WH_WC);

    (void)hipMemsetAsync(curs, 0, NNODE * sizeof(int), stream);
    k_prep<<<SCAT_BLOCKS + 21, 256, 0, stream>>>(src, dst, rtype, curs, smeta,
                                                 rel_table, Wr, br, We, be,
                                                 attn_r, attn_rs, attn_s, W, prep, wfrag);

    (void)hipFuncSetAttribute((const void*)k_fused, hipFuncAttributeMaxDynamicSharedMemorySize, S_TOTAL);
    k_fused<<<NGRAPH, 512, S_TOTAL, stream>>>(state, rw, code_emb, h_bias, be,
                                              attn_h, attn_t, node_ids, curs, smeta,
                                              prep, wfrag, wc, xout, relOut, edgeOut);
}

// Round 20
// 168.286 us; speedup vs baseline: 1.1473x; 1.1473x over previous
//
#include <hip/hip_runtime.h>
#include <hip/hip_fp16.h>

#define DI __device__ __forceinline__

constexpr int NGRAPH = 500;
constexpr int EDGES  = 800000;
constexpr int NNODE  = 50000;
constexpr int CAP    = 64;            // slots per dst bin (Poisson mean 16; pow2 for shifts)
constexpr int SCAT_BLOCKS = (EDGES + 255) / 256;   // 3125

// ---- workspace layout (4-byte units) ----
constexpr size_t WI_CURS  = 0;                               // [50000]
constexpr size_t WI_SMETA = 50048;                           // [50000*64]
constexpr size_t WF_PREP  = WI_SMETA + (size_t)NNODE * CAP;  // 656 floats (pad 672)
constexpr size_t WF_WFRAG = WF_PREP + 672;                   // uint4[5120] (20480 words)
constexpr size_t WH_WC    = WF_WFRAG + 20480;                // f16[NGRAPH*2048*4]

// ---- LDS layout (bytes), total 151496 -> 1 block/CU ----
constexpr int S_H    = 0;        // f16 h[100][40] (cols 0..31 used)
constexpr int S_HP   = 8000;     // f16 hp[100][128] (col c -> d=c>>2,h=c&3), XOR-swizzled
constexpr int S_U    = 33600;    // f16 U[100][516]
constexpr int S_EH   = 136800;   // f32[100][4]
constexpr int S_ET   = 138400;   // f32[100][4]
constexpr int S_DEN  = 140000;   // f32[100][4]
constexpr int S_RA   = 141600;   // f32[16][4]
constexpr int S_ESG  = 141856;   // f32[4]
constexpr int S_AH   = 141872;   // f32[128] attn_h in hp-col order
constexpr int S_AT   = 142384;   // f32[128]
constexpr int S_MLDS = 142896;   // i32[2048] dst-sorted edge meta
constexpr int S_RP   = 151088;   // i32[102] rowptr
constexpr int S_TOTAL = 151496;
constexpr int UROW = 516;

typedef _Float16 f16x8 __attribute__((ext_vector_type(8)));
typedef _Float16 f16x2 __attribute__((ext_vector_type(2)));
typedef float f32x4 __attribute__((ext_vector_type(4)));

DI float lrelu(float x) { return x >= 0.f ? x : 0.2f * x; }
DI f16x8 u4_to_f16x8(uint4 u) { f16x8 r; __builtin_memcpy(&r, &u, 16); return r; }
DI f16x8 two_u2(uint2 a, uint2 b) { return u4_to_f16x8(make_uint4(a.x, a.y, b.x, b.y)); }
DI float h2f(unsigned short u) { __half hv; __builtin_memcpy(&hv, &u, 2); return __half2float(hv); }

// f32 += half2 . half2 via v_dot2_f32_f16
DI float fdot2u(unsigned a, unsigned b, float c) {
    f16x2 av, bv;
    __builtin_memcpy(&av, &a, 4);
    __builtin_memcpy(&bv, &b, 4);
    return __builtin_amdgcn_fdot2(av, bv, c, false);
}

// hp swizzle: half-index for (node n, col c); XOR bits 3..5 with n&7 (16B granularity)
DI int hpIdx(int n, int c) { return n * 128 + (c ^ ((n & 7) << 3)); }

// ---------------- merged prep: scatter-by-dst + prep folds + MFMA fragments ----------------
__global__ void k_prep(const int* __restrict__ src, const int* __restrict__ dst,
                       const int* __restrict__ rt, int* __restrict__ curs,
                       int* __restrict__ smeta,
                       const float* __restrict__ rel_table, const float* __restrict__ Wr,
                       const float* __restrict__ br, const float* __restrict__ We,
                       const float* __restrict__ be, const float* __restrict__ attn_r,
                       const float* __restrict__ attn_rs, const float* __restrict__ attn_s,
                       const float* __restrict__ W, float* __restrict__ prep,
                       uint4* __restrict__ wf) {
    __shared__ float wra[2][32][4];
    __shared__ float sbias[2][3][4];
    int bb = blockIdx.x, t = threadIdx.x;
    if (bb < SCAT_BLOCKS) {
        int e = bb * 256 + t;
        if (e >= EDGES) return;
        int s = src[e], d = dst[e], r = rt[e];
        int g = (unsigned)d / 100u;
        int pos = atomicAdd(&curs[d], 1);
        if (pos < CAP)
            smeta[((size_t)d << 6) + pos] = (s - g * 100) | (r << 7) | (e << 11);
        return;
    }
    int b = bb - SCAT_BLOCKS;
    if (b == 0) {
        {
            int l = t >> 7, k = (t >> 2) & 31, h = t & 3;
            float a = 0.f, b2 = 0.f, c = 0.f;
            for (int d2 = 0; d2 < 32; ++d2) {
                float w1 = Wr[(size_t)(l*32 + k)*128 + h*32 + d2];
                float w2 = We[(size_t)(l*32 + k)*128 + h*32 + d2];
                a  += w1 * attn_r [l*128 + h*32 + d2];
                b2 += w1 * attn_rs[l*128 + h*32 + d2];
                c  += w2 * attn_s [l*128 + h*32 + d2];
            }
            wra[l][k][h] = a;
            prep[128 + (l*32 + k)*4 + h] = b2;
            prep[384 + (l*32 + k)*4 + h] = c;
        }
        if (t < 24) {
            int l = t / 12, which = (t % 12) / 4, h = t % 4;
            const float* bp = (which == 2) ? be : br;
            const float* ap = (which == 0) ? attn_r : (which == 1 ? attn_rs : attn_s);
            float s = 0.f;
            for (int d2 = 0; d2 < 32; ++d2) s += bp[l*128 + h*32 + d2] * ap[l*128 + h*32 + d2];
            sbias[l][which][h] = s;
        }
        __syncthreads();
        if (t < 128) {
            int l = t >> 6, r = (t >> 2) & 15, h = t & 3;
            float s = sbias[l][0][h];
            for (int k = 0; k < 32; ++k) s += rel_table[r*32 + k] * wra[l][k][h];
            prep[(l*16 + r)*4 + h] = s;
        }
        if (t < 8) {
            int l = t >> 2, h = t & 3;
            prep[640 + l*4 + h] = sbias[l][1][h];
            prep[648 + l*4 + h] = sbias[l][2][h];
        }
    } else if (b <= 16) {
        // W fragments (f16): wf[((l*16+rel)*2+Nt)*64 + ln]
        int fi = (b - 1) * 256 + t;
        int ln = fi & 63, Nt = (fi >> 6) & 1, rel = (fi >> 7) & 15, l = fi >> 11;
        int j = Nt*16 + (ln & 15), k0 = (ln >> 4) << 3;
        unsigned short fr[8];
        #pragma unroll
        for (int i = 0; i < 8; ++i) {
            __half hv = __float2half(W[(((size_t)l*16 + rel)*32 + k0 + i)*32 + j]);
            __builtin_memcpy(&fr[i], &hv, 2);
        }
        uint4 o;
        o.x = fr[0] | ((unsigned)fr[1] << 16);
        o.y = fr[2] | ((unsigned)fr[3] << 16);
        o.z = fr[4] | ((unsigned)fr[5] << 16);
        o.w = fr[6] | ((unsigned)fr[7] << 16);
        wf[fi] = o;
    } else {
        // We fragments (f16, column-permuted): col c -> phys (c&3)*32+(c>>2)
        int fi = (b - 17) * 256 + t;
        int ln = fi & 63, Nt = (fi >> 6) & 7, l = fi >> 9;
        int c = Nt*16 + (ln & 15);
        int phys = (c & 3)*32 + (c >> 2);
        int k0 = (ln >> 4) << 3;
        unsigned short fr[8];
        #pragma unroll
        for (int i = 0; i < 8; ++i) {
            __half hv = __float2half(We[(size_t)l*4096 + (k0 + i)*128 + phys]);
            __builtin_memcpy(&fr[i], &hv, 2);
        }
        uint4 o;
        o.x = fr[0] | ((unsigned)fr[1] << 16);
        o.y = fr[2] | ((unsigned)fr[3] << 16);
        o.z = fr[4] | ((unsigned)fr[5] << 16);
        o.w = fr[6] | ((unsigned)fr[7] << 16);
        wf[4096 + fi] = o;
    }
}

// ---------------- fused per-graph forward: owner-computes, zero LDS atomics ----------------
__global__ void __launch_bounds__(1024, 1)
k_fused(const float* __restrict__ state, const float* __restrict__ rw,
        const float* __restrict__ code_emb, const float* __restrict__ h_bias,
        const float* __restrict__ be, const float* __restrict__ attn_h,
        const float* __restrict__ attn_t, const int* __restrict__ node_ids,
        const int* __restrict__ curs, const int* __restrict__ smeta,
        const float* __restrict__ prep, const uint4* __restrict__ wf,
        unsigned short* __restrict__ wc,
        float* __restrict__ xout, float* __restrict__ relOut, float* __restrict__ edgeOut) {
    extern __shared__ char smem[];
    __half* hH  = (__half*)(smem + S_H);
    __half* hpH = (__half*)(smem + S_HP);
    __half* Uh  = (__half*)(smem + S_U);
    float* ehp  = (float*)(smem + S_EH);
    float* etp  = (float*)(smem + S_ET);
    float* denp = (float*)(smem + S_DEN);
    float* rap  = (float*)(smem + S_RA);
    float* esgp = (float*)(smem + S_ESG);
    float* sAH  = (float*)(smem + S_AH);
    float* sAT  = (float*)(smem + S_AT);
    int*   mlds = (int*)(smem + S_MLDS);
    int*   rp   = (int*)(smem + S_RP);
    const uint4* wfe = wf + 4096;

    const int g = blockIdx.x;
    const int t = threadIdx.x;
    const int lane = t & 63, w = t >> 6;          // 16 waves
    const int ln15 = lane & 15, q = lane >> 4, q8 = q << 3;
    const int MtA = w % 7, NtA = w / 7;
    const bool hasT = (w < 14);
    const int cg = w >> 1;
    const int colc = cg * 16 + ln15;
    const int physc = (colc & 3) * 32 + (colc >> 2);
    const int Mt0 = (w & 1) ? 4 : 0;
    const int Mt1 = (w & 1) ? 7 : 4;

    unsigned short* wcg = wc + ((size_t)g << 13);     // 2048 edges x 4 halves
    const uint2* wcu = (const uint2*)wcg;

    // P0: h0 = code_emb[node_ids]; rowptr scan; CSR stage
    for (int i = t; i < 1600; i += 1024) {
        int n = i >> 4, dp = i & 15;
        int id = node_ids[g * 100 + n];
        float2 v = *(const float2*)&code_emb[(size_t)id * 32 + dp * 2];
        *(__half2*)&hH[n * 40 + dp * 2] = __floats2half2_rn(v.x, v.y);
    }
    if (t < 100) { int c = curs[g * 100 + t]; rp[t + 1] = c < CAP ? c : CAP; }
    if (t == 0) rp[0] = 0;
    __syncthreads();
    for (int o = 1; o < 128; o <<= 1) {
        int v = 0;
        if (t <= 100 && t >= o) v = rp[t - o];
        __syncthreads();
        if (t <= 100 && t >= o) rp[t] += v;
        __syncthreads();
    }
    for (int i = t; i < 100 * CAP; i += 1024) {
        int bin = i >> 6, pos = i & 63;
        int lo = rp[bin], cnt = rp[bin + 1] - lo;
        if (pos < cnt)
            mlds[lo + pos] = smeta[(((size_t)(g * 100 + bin)) << 6) + pos];
    }

    for (int l = 0; l < 2; ++l) {
        __syncthreads();   // B0: h/CSR ready, U free

        // ---- X1: zero U; stage sAH/sAT; MFMA hp = h@We + be; P1 rel-att ----
        for (int i = t; i < 6450; i += 1024) ((uint4*)(smem + S_U))[i] = make_uint4(0, 0, 0, 0);
        if (t < 128) {
            sAH[t] = attn_h[l * 128 + (t & 3) * 32 + (t >> 2)];
            sAT[t] = attn_t[l * 128 + (t & 3) * 32 + (t >> 2)];
        }
        {
            uint4 bwe = wfe[(l * 8 + cg) * 64 + lane];
            f16x8 bw = u4_to_f16x8(bwe);
            float beC = be[l * 128 + physc];
            f32x4 z = {0.f, 0.f, 0.f, 0.f};
            for (int Mt = Mt0; Mt < Mt1; ++Mt) {
                const __half* hr = hH + (Mt * 16 + ln15) * 40 + q8;
                f32x4 pc = __builtin_amdgcn_mfma_f32_16x16x32_f16(
                    two_u2(*(const uint2*)hr, *(const uint2*)(hr + 4)), bw, z, 0, 0, 0);
                #pragma unroll
                for (int i = 0; i < 4; ++i) {
                    int n = Mt * 16 + q * 4 + i;
                    if (n < 100) hpH[hpIdx(n, colc)] = __float2half(pc[i] + beC);
                }
            }
        }
        {   // P1: relation attention (all waves redundantly; benign identical writes)
            int k32 = lane & 31;
            float sG = state[g * 32 + k32];
            float4 frs = *(const float4*)&prep[128 + l * 128 + k32 * 4];
            float4 fes = *(const float4*)&prep[384 + l * 128 + k32 * 4];
            float p0 = sG * frs.x, p1 = sG * frs.y, p2 = sG * frs.z, p3 = sG * frs.w;
            float q0 = sG * fes.x, q1 = sG * fes.y, q2 = sG * fes.z, q3 = sG * fes.w;
            #pragma unroll
            for (int m = 1; m < 32; m <<= 1) {
                p0 += __shfl_xor(p0, m); p1 += __shfl_xor(p1, m);
                p2 += __shfl_xor(p2, m); p3 += __shfl_xor(p3, m);
                q0 += __shfl_xor(q0, m); q1 += __shfl_xor(q1, m);
                q2 += __shfl_xor(q2, m); q3 += __shfl_xor(q3, m);
            }
            int h = lane & 3;
            float esh  = (h & 2) ? ((h & 1) ? p3 : p2) : ((h & 1) ? p1 : p0);
            float esgh = (h & 2) ? ((h & 1) ? q3 : q2) : ((h & 1) ? q1 : q0);
            esh  += prep[640 + l * 4 + h];
            esgh += prep[648 + l * 4 + h];
            if (lane < 4) esgp[lane] = esgh;
            float er = prep[l * 64 + lane];
            float ex = __expf(lrelu(er + esh));
            float s = ex;
            s += __shfl_xor(s, 4); s += __shfl_xor(s, 8);
            s += __shfl_xor(s, 16); s += __shfl_xor(s, 32);
            rap[lane] = ex / s;
        }
        __syncthreads();   // B1: hp/sAH/sAT/rap/esg ready, U zeroed

        // ---- A0: eh/et per src node (owner = s; no atomics) ----
        if (t < 100) {
            int s = t;
            int sw = (s & 7) << 3;
            float eh[4] = {0, 0, 0, 0}, et[4] = {0, 0, 0, 0};
            #pragma unroll 4
            for (int i = 0; i < 16; ++i) {
                uint4 hv = *(const uint4*)&hpH[s * 128 + ((i * 8) ^ sw)];
                unsigned short hu[8];
                __builtin_memcpy(hu, &hv, 16);
                #pragma unroll
                for (int k = 0; k < 8; ++k) {
                    float f = h2f(hu[k]);
                    eh[k & 3] += f * sAH[i * 8 + k];
                    et[k & 3] += f * sAT[i * 8 + k];
                }
            }
            *(float4*)&ehp[s * 4] = make_float4(eh[0], eh[1], eh[2], eh[3]);
            *(float4*)&etp[s * 4] = make_float4(et[0], et[1], et[2], et[3]);
        }
        __syncthreads();   // B1b: eh/et ready

        // ---- A: den per (dst, head); then write packed coefficients to global wc ----
        if (t < 400) {
            int d = t >> 2, h = t & 3;
            int lo = rp[d], hi = rp[d + 1];
            float etd = etp[d * 4 + h] + esgp[h];
            float den = 0.f;
            for (int e = lo; e < hi; ++e) {
                int m = mlds[e];
                den += __expf(lrelu(ehp[(m & 127) * 4 + h] + etd));
            }
            denp[d * 4 + h] = den;
            float inv = 1.f / den;
            bool wAtt = (l == 1);
            for (int e = lo; e < hi; ++e) {
                int m = mlds[e];
                int r = (m >> 7) & 15;
                float a = __expf(lrelu(ehp[(m & 127) * 4 + h] + etd)) * inv;
                __half ch = __float2half(a * rap[r * 4 + h]);
                __builtin_memcpy(&wcg[e * 4 + h], &ch, 2);
                if (wAtt) {
                    int oe = (m >> 11) & 0xFFFFF;
                    edgeOut[(size_t)oe * 4 + h] = a;
                    relOut[(size_t)oe * 4 + h] = rap[r * 4 + h];
                }
            }
        }
        __syncthreads();   // B2: den + wc ready (vmcnt drained by barrier)

        // ---- B: U accumulation per (dst, dim-quad) (coef from wc; fdot2 + pk_add) ----
        if (t < 800) {
            int d = t >> 3, j = t & 7;          // dims [j*4, j*4+4)
            int lo = rp[d], hi = rp[d + 1];
            for (int e = lo; e < hi; ++e) {
                int m = mlds[e];
                int s = m & 127, r = (m >> 7) & 15;
                uint2 cc = wcu[e];
                int sw = (s & 7) << 3;
                uint4 hv0 = *(const uint4*)&hpH[s * 128 + ((j * 16) ^ sw)];
                uint4 hv1 = *(const uint4*)&hpH[s * 128 + ((j * 16 + 8) ^ sw)];
                float v0 = fdot2u(cc.x, hv0.x, fdot2u(cc.y, hv0.y, 0.f));
                float v1 = fdot2u(cc.x, hv0.z, fdot2u(cc.y, hv0.w, 0.f));
                float v2 = fdot2u(cc.x, hv1.x, fdot2u(cc.y, hv1.y, 0.f));
                float v3 = fdot2u(cc.x, hv1.z, fdot2u(cc.y, hv1.w, 0.f));
                __half2 v01 = __floats2half2_rn(v0, v1);
                __half2 v23 = __floats2half2_rn(v2, v3);
                __half2* up = (__half2*)(Uh + d * UROW + r * 32 + j * 4);
                up[0] = __hadd2(up[0], v01);
                up[1] = __hadd2(up[1], v23);
            }
        }
        __syncthreads();   // B3: U complete

        // ---- P7: 16-relation MFMA chain (waves 0..13) ----
        f32x4 accA = {0.f, 0.f, 0.f, 0.f};
        if (hasT) {
            #pragma unroll 4
            for (int rel = 0; rel < 16; ++rel) {
                uint4 bAu = wf[((l * 16 + rel) * 2 + NtA) * 64 + lane];
                const __half* up = Uh + (MtA * 16 + ln15) * UROW + rel * 32 + q8;
                f16x8 af = two_u2(*(const uint2*)up, *(const uint2*)(up + 4));
                accA = __builtin_amdgcn_mfma_f32_16x16x32_f16(af, u4_to_f16x8(bAu), accA, 0, 0, 0);
            }
        }
        // P8: h = relu(0.5*(agg+bias) + 0.5*h)
        if (hasT) {
            int dcol = NtA * 16 + ln15;
            float bias = h_bias[l * 32 + dcol];
            #pragma unroll
            for (int i = 0; i < 4; ++i) {
                int n = MtA * 16 + q * 4 + i;
                if (n < 100) {
                    float hold = __half2float(hH[n * 40 + dcol]);
                    float hn = fmaxf(0.f, 0.5f * (accA[i] + bias) + 0.5f * hold);
                    hH[n * 40 + dcol] = __float2half(hn);
                }
            }
        }
    }
    __syncthreads();   // h final

    // P9: readout x[g] = sum_n h[n] * rw[n]   (red buffer reuses U region)
    float* redp = (float*)(smem + S_U);
    {
        int part = t >> 5, d = t & 31;
        float acc = 0.f;
        for (int n = part; n < 100; n += 32)
            acc += __half2float(hH[n * 40 + d]) * rw[g * 100 + n];
        redp[part * 32 + d] = acc;
    }
    __syncthreads();
    if (t < 32) {
        float s = 0.f;
        #pragma unroll
        for (int p = 0; p < 32; ++p) s += redp[p * 32 + t];
        xout[g * 32 + t] = s;
    }
}

extern "C" void kernel_launch(void* const* d_in, const int* in_sizes, int n_in,
                              void* d_out, int out_size, void* d_ws, size_t ws_size,
                              hipStream_t stream) {
    const float* state     = (const float*)d_in[0];
    const float* rw        = (const float*)d_in[1];
    const float* code_emb  = (const float*)d_in[2];
    const float* rel_table = (const float*)d_in[3];
    const float* W         = (const float*)d_in[4];
    const float* h_bias    = (const float*)d_in[5];
    const float* Wr        = (const float*)d_in[6];
    const float* br        = (const float*)d_in[7];
    const float* We        = (const float*)d_in[8];
    const float* be        = (const float*)d_in[9];
    const float* attn_h    = (const float*)d_in[10];
    const float* attn_t    = (const float*)d_in[11];
    const float* attn_s    = (const float*)d_in[12];
    const float* attn_r    = (const float*)d_in[13];
    const float* attn_rs   = (const float*)d_in[14];
    const int* node_ids    = (const int*)d_in[15];
    const int* src         = (const int*)d_in[16];
    const int* dst         = (const int*)d_in[17];
    const int* rtype       = (const int*)d_in[18];

    float* out = (float*)d_out;
    float* xout = out;
    float* relOut = out + (size_t)NGRAPH * 32;
    float* edgeOut = relOut + (size_t)EDGES * 4;

    int* wsi = (int*)d_ws;
    float* wsf = (float*)d_ws;
    int* curs   = wsi + WI_CURS;
    int* smeta  = wsi + WI_SMETA;
    float* prep = wsf + WF_PREP;
    uint4* wfrag = (uint4*)(wsf + WF_WFRAG);
    unsigned short* wc = (unsigned short*)(wsf + WH_WC);

    (void)hipMemsetAsync(curs, 0, NNODE * sizeof(int), stream);
    k_prep<<<SCAT_BLOCKS + 21, 256, 0, stream>>>(src, dst, rtype, curs, smeta,
                                                 rel_table, Wr, br, We, be,
                                                 attn_r, attn_rs, attn_s, W, prep, wfrag);

    (void)hipFuncSetAttribute((const void*)k_fused, hipFuncAttributeMaxDynamicSharedMemorySize, S_TOTAL);
    k_fused<<<NGRAPH, 1024, S_TOTAL, stream>>>(state, rw, code_emb, h_bias, be,
                                               attn_h, attn_t, node_ids, curs, smeta,
                                               prep, wfrag, wc, xout, relOut, edgeOut);
}